// Round 10
// baseline (318.284 us; speedup 1.0000x reference)
//
#include <hip/hip_runtime.h>

// NT-Xent / NCE loss: 2 kernels, no grid barrier (completion-counter fusion).
// K1: W = [normalize(x1);normalize(x2)] split into Whi+Wlo (bf16 pair); zero S, done[].
// K2: upper-triangular 128x128 Gram tiles (3xMFMA split precision), fused exp
//     row+col sums into S; each row-block of S has exactly 64 contributing tiles;
//     the 64th contributor (done[b] counter) computes loss for those 128 rows inline.
// loss[r] = log( sum_{j!=r} exp(10*dot(r,j) - 10) ) + 10 - 10*dot(r, partner(r))

#define N_ROWS 4096
#define D      256
#define TWO_N  8192
#define NTILE  64
#define NTRI   (NTILE * (NTILE + 1) / 2)   // 2080

typedef __attribute__((ext_vector_type(8))) short bf16x8;
typedef __attribute__((ext_vector_type(4))) float f32x4;

#define MFMA16(a, b, c) __builtin_amdgcn_mfma_f32_16x16x32_bf16((a), (b), (c), 0, 0, 0)

static __device__ __forceinline__ float bf2f(unsigned short b) {
    return __uint_as_float(((unsigned)b) << 16);
}
static __device__ __forceinline__ unsigned short f2bf(float x) {  // RNE
    unsigned u = __float_as_uint(x);
    return (unsigned short)((u + 0x7FFF + ((u >> 16) & 1)) >> 16);
}
static __device__ __forceinline__ void gload16(const void* g, void* l) {
    __builtin_amdgcn_global_load_lds((const __attribute__((address_space(1))) void*)g,
                                     (__attribute__((address_space(3))) void*)l, 16, 0, 0);
}

// ---------------- K1: normalize + bf16 hi/lo split; zero S and done ----------------
__global__ __launch_bounds__(256) void normalize_k(const float* __restrict__ x1,
                                                   const float* __restrict__ x2,
                                                   unsigned short* __restrict__ Whi,
                                                   unsigned short* __restrict__ Wlo,
                                                   float* __restrict__ S,
                                                   unsigned* __restrict__ done) {
    if (blockIdx.x < 32) S[(blockIdx.x << 8) | threadIdx.x] = 0.f;   // 32*256 = 8192
    if (blockIdx.x == 32 && threadIdx.x < NTILE) done[threadIdx.x] = 0u;

    int row  = (int)((blockIdx.x * blockDim.x + threadIdx.x) >> 6);
    int lane = threadIdx.x & 63;
    const float* src = (row < N_ROWS) ? (x1 + (size_t)row * D)
                                      : (x2 + (size_t)(row - N_ROWS) * D);
    float4 v = ((const float4*)src)[lane];
    float ss = v.x * v.x + v.y * v.y + v.z * v.z + v.w * v.w;
    #pragma unroll
    for (int off = 32; off > 0; off >>= 1) ss += __shfl_xor(ss, off);
    float scale = 1.0f / fmaxf(sqrtf(ss), 1e-8f);
    float a[4] = {v.x * scale, v.y * scale, v.z * scale, v.w * scale};
    ushort4 h, l;
    unsigned short* hp = (unsigned short*)&h;
    unsigned short* lp = (unsigned short*)&l;
    #pragma unroll
    for (int i = 0; i < 4; ++i) {
        hp[i] = f2bf(a[i]);
        lp[i] = f2bf(a[i] - bf2f(hp[i]));
    }
    ((ushort4*)(Whi + (size_t)row * D))[lane] = h;
    ((ushort4*)(Wlo + (size_t)row * D))[lane] = l;
}

// Finalize 128 rows of a row-block: loss = log(S) + 10 - 10*pos_dot.
static __device__ __forceinline__ void finalize_rows(int b,
        const unsigned short* __restrict__ Whi, const unsigned short* __restrict__ Wlo,
        const float* __restrict__ S, float* __restrict__ out, int wv, int lane) {
    for (int r = wv; r < 128; r += 4) {                 // 4 waves x 32 rows
        int row = b * 128 + r;
        int partner = (row < N_ROWS) ? row + N_ROWS : row - N_ROWS;
        ushort4 ah = ((const ushort4*)(Whi + (size_t)row * D))[lane];
        ushort4 al = ((const ushort4*)(Wlo + (size_t)row * D))[lane];
        ushort4 bh = ((const ushort4*)(Whi + (size_t)partner * D))[lane];
        ushort4 bl = ((const ushort4*)(Wlo + (size_t)partner * D))[lane];
        const unsigned short* ahp = (const unsigned short*)&ah;
        const unsigned short* alp = (const unsigned short*)&al;
        const unsigned short* bhp = (const unsigned short*)&bh;
        const unsigned short* blp = (const unsigned short*)&bl;
        float d = 0.f;
        #pragma unroll
        for (int i = 0; i < 4; ++i) {
            float a = bf2f(ahp[i]) + bf2f(alp[i]);
            float bb = bf2f(bhp[i]) + bf2f(blp[i]);
            d = fmaf(a, bb, d);
        }
        #pragma unroll
        for (int off = 32; off > 0; off >>= 1) d += __shfl_xor(d, off);
        if (lane == 0) {
            float sval = __hip_atomic_load(&S[row], __ATOMIC_RELAXED,
                                           __HIP_MEMORY_SCOPE_AGENT);
            out[row] = logf(sval) + 10.0f - 10.0f * d;
        }
    }
}

// ---------------- K2: triangular Gram tiles + exp sums + last-block finalize ----
// Grid: 2080 blocks (XCD-swizzled), 4 waves (2x2). Tile body identical to R6
// (62.3 us verified): swizzled granules, global_load_lds w16, conflict-free.
__global__ __launch_bounds__(256, 3) void nce_partial_k(const unsigned short* __restrict__ Whi,
                                                        const unsigned short* __restrict__ Wlo,
                                                        float* __restrict__ S,
                                                        unsigned* __restrict__ done,
                                                        float* __restrict__ out) {
    __shared__ unsigned short tile[4][4096];   // Ahi, Alo, Bhi, Blo: 128x32 bf16, swizzled
    __shared__ float Srow[128];
    __shared__ float Scol[128];
    __shared__ int win_i, win_j;

    const int tid  = threadIdx.x;
    const int wid  = tid >> 6, lane = tid & 63;
    const int lr   = lane & 15, lg = lane >> 4;
    const int wr   = wid >> 1,  wc = wid & 1;

    // XCD-contiguous triangular tile id (2080 % 8 == 0 -> bijective)
    const int t = (blockIdx.x & 7) * (NTRI / 8) + (blockIdx.x >> 3);
    #define FPC(i) ((i) * NTILE - (i) * ((i) - 1) / 2)
    int bi = (int)((129.0f - sqrtf((float)(129 * 129 - 8 * t))) * 0.5f);
    while (FPC(bi + 1) <= t) ++bi;
    while (FPC(bi) > t) --bi;
    const int bj = bi + (t - FPC(bi));
    const int q0 = bi * 128, c0 = bj * 128;
    const bool offdiag = (bi != bj);

    if (tid < 128) { Srow[tid] = 0.f; Scol[tid] = 0.f; }

    f32x4 acc[4][4];
    #pragma unroll
    for (int i = 0; i < 4; ++i)
        #pragma unroll
        for (int j = 0; j < 4; ++j) acc[i][j] = (f32x4)0.f;

    // staging source offsets (pre-swizzled so LDS dest stays linear; rule #21)
    const int j0 = tid, j1 = tid + 256;
    const int r0 = j0 >> 2, g0 = (j0 & 3) ^ ((r0 >> 1) & 3);
    const int r1 = j1 >> 2, g1 = (j1 & 3) ^ ((r1 >> 1) & 3);
    const size_t soff0 = (size_t)r0 * D + g0 * 8;
    const size_t soff1 = (size_t)r1 * D + g1 * 8;
    const unsigned short* srcAh = Whi + (size_t)q0 * D;
    const unsigned short* srcAl = Wlo + (size_t)q0 * D;
    const unsigned short* srcBh = Whi + (size_t)c0 * D;
    const unsigned short* srcBl = Wlo + (size_t)c0 * D;
    const unsigned db0 = (unsigned)(tid & ~63) * 16u;          // wave-uniform LDS byte base
    const unsigned db1 = db0 + 256u * 16u;

    // fragment LDS byte offsets: slot(row,g) = row*4 + (g ^ ((row>>1)&3)) -> conflict-free
    int offA[4], offB[4];
    #pragma unroll
    for (int s = 0; s < 4; ++s) {
        int rowA = wr * 64 + s * 16 + lr;
        int rowB = wc * 64 + s * 16 + lr;
        int x = lg ^ ((lr >> 1) & 3);
        offA[s] = (rowA * 4 + x) * 16;
        offB[s] = (rowB * 4 + x) * 16;
    }

    for (int kc = 0; kc < D; kc += 32) {
        __syncthreads();   // previous chunk's reads done -> LDS reusable
        gload16(srcAh + soff0 + kc, (char*)&tile[0][0] + db0);
        gload16(srcAh + soff1 + kc, (char*)&tile[0][0] + db1);
        gload16(srcAl + soff0 + kc, (char*)&tile[1][0] + db0);
        gload16(srcAl + soff1 + kc, (char*)&tile[1][0] + db1);
        gload16(srcBh + soff0 + kc, (char*)&tile[2][0] + db0);
        gload16(srcBh + soff1 + kc, (char*)&tile[2][0] + db1);
        gload16(srcBl + soff0 + kc, (char*)&tile[3][0] + db0);
        gload16(srcBl + soff1 + kc, (char*)&tile[3][0] + db1);
        __syncthreads();   // compiler drains vmcnt before s_barrier

        bf16x8 bh[4], bl[4];
        #pragma unroll
        for (int sj = 0; sj < 4; ++sj) {
            bh[sj] = *(const bf16x8*)((const char*)&tile[2][0] + offB[sj]);
            bl[sj] = *(const bf16x8*)((const char*)&tile[3][0] + offB[sj]);
        }
        #pragma unroll
        for (int si = 0; si < 4; ++si) {
            bf16x8 ah = *(const bf16x8*)((const char*)&tile[0][0] + offA[si]);
            bf16x8 al = *(const bf16x8*)((const char*)&tile[1][0] + offA[si]);
            #pragma unroll
            for (int sj = 0; sj < 4; ++sj) {
                acc[si][sj] = MFMA16(ah, bh[sj], acc[si][sj]);
                acc[si][sj] = MFMA16(ah, bl[sj], acc[si][sj]);
                acc[si][sj] = MFMA16(al, bh[sj], acc[si][sj]);
            }
        }
    }

    // epilogue: exp + self-mask; row-sums always, col-sums for off-diag tiles.
    // C/D map: row = (lane>>4)*4 + reg, col = lane&15
    float rs[4][4];
    float cs[4] = {0.f, 0.f, 0.f, 0.f};
    #pragma unroll
    for (int si = 0; si < 4; ++si)
        #pragma unroll
        for (int r = 0; r < 4; ++r) rs[si][r] = 0.f;

    #pragma unroll
    for (int si = 0; si < 4; ++si) {
        int grb = q0 + wr * 64 + si * 16 + lg * 4;
        #pragma unroll
        for (int sj = 0; sj < 4; ++sj) {
            int gc = c0 + wc * 64 + sj * 16 + lr;
            #pragma unroll
            for (int r = 0; r < 4; ++r) {
                float e = __expf(fmaf(10.f, acc[si][sj][r], -10.f));
                e = (grb + r == gc) ? 0.f : e;
                rs[si][r] += e;
                cs[sj]    += e;
            }
        }
    }
    #pragma unroll
    for (int off = 1; off < 16; off <<= 1)
        #pragma unroll
        for (int si = 0; si < 4; ++si)
            #pragma unroll
            for (int r = 0; r < 4; ++r) rs[si][r] += __shfl_xor(rs[si][r], off);
    if (lr == 0) {
        #pragma unroll
        for (int si = 0; si < 4; ++si)
            #pragma unroll
            for (int r = 0; r < 4; ++r)
                atomicAdd(&Srow[wr * 64 + si * 16 + lg * 4 + r], rs[si][r]);
    }
    if (offdiag) {
        #pragma unroll
        for (int sj = 0; sj < 4; ++sj) {
            cs[sj] += __shfl_xor(cs[sj], 16);
            cs[sj] += __shfl_xor(cs[sj], 32);
        }
        if (lg == 0) {
            #pragma unroll
            for (int sj = 0; sj < 4; ++sj)
                atomicAdd(&Scol[wc * 64 + sj * 16 + lr], cs[sj]);
        }
    }
    __syncthreads();
    if (tid < 128) {
        atomicAdd(&S[q0 + tid], Srow[tid]);
        if (offdiag) atomicAdd(&S[c0 + tid], Scol[tid]);
    }
    __syncthreads();   // drains the S atomics (vmcnt) for the whole block

    // completion counters: each row-block has exactly 64 contributing tiles.
    // Wait-free: nobody spins; the 64th contributor finalizes those 128 rows.
    if (tid == 0) {
        __threadfence();   // belt-and-braces: adds visible before counter bump
        unsigned oi = __hip_atomic_fetch_add(&done[bi], 1u, __ATOMIC_ACQ_REL,
                                             __HIP_MEMORY_SCOPE_AGENT);
        win_i = (oi == 63u);
        win_j = 0;
        if (offdiag) {
            unsigned oj = __hip_atomic_fetch_add(&done[bj], 1u, __ATOMIC_ACQ_REL,
                                                 __HIP_MEMORY_SCOPE_AGENT);
            win_j = (oj == 63u);
        }
    }
    __syncthreads();
    if (win_i) finalize_rows(bi, Whi, Wlo, S, out, wid, lane);
    if (win_j) finalize_rows(bj, Whi, Wlo, S, out, wid, lane);
}

extern "C" void kernel_launch(void* const* d_in, const int* in_sizes, int n_in,
                              void* d_out, int out_size, void* d_ws, size_t ws_size,
                              hipStream_t stream) {
    const float* x1 = (const float*)d_in[0];
    const float* x2 = (const float*)d_in[1];
    float* out = (float*)d_out;

    unsigned short* Whi = (unsigned short*)d_ws;                    // 4 MB
    unsigned short* Wlo = Whi + (size_t)TWO_N * D;                  // 4 MB
    float* S = (float*)(Wlo + (size_t)TWO_N * D);                   // 32 KB
    unsigned* done = (unsigned*)(S + TWO_N);                        // 64 u32

    normalize_k<<<TWO_N / 4, 256, 0, stream>>>(x1, x2, Whi, Wlo, S, done);
    nce_partial_k<<<NTRI, 256, 0, stream>>>(Whi, Wlo, S, done, out);
}

// Round 14
// 181.196 us; speedup vs baseline: 1.7566x; 1.7566x over previous
//
#include <hip/hip_runtime.h>

// NT-Xent / NCE loss: 2 kernels, completion-counter fusion, ALL-RELAXED atomics.
// R10 lesson: ACQ_REL/threadfence at agent scope emit buffer_inv/buffer_wbl2
// (full per-XCD L2 invalidate) on gfx950 -> 4.3x slowdown. Not needed: S-adds
// are cache-bypassing device-scope atomics; __syncthreads drains vmcnt, so
// program order + coherent-point serialization already give the guarantee.
// K1: W = [normalize(x1);normalize(x2)] -> Whi+Wlo (bf16 pair); zero S, done[].
// K2: upper-tri 128x128 Gram tiles (3xMFMA split precision), fused exp row+col
//     sums into S; 64th contributor per row-block finalizes its 128 losses.
// loss[r] = log( sum_{j!=r} exp(10*dot(r,j) - 10) ) + 10 - 10*dot(r, partner(r))

#define N_ROWS 4096
#define D      256
#define TWO_N  8192
#define NTILE  64
#define NTRI   (NTILE * (NTILE + 1) / 2)   // 2080

typedef __attribute__((ext_vector_type(8))) short bf16x8;
typedef __attribute__((ext_vector_type(4))) float f32x4;

#define MFMA16(a, b, c) __builtin_amdgcn_mfma_f32_16x16x32_bf16((a), (b), (c), 0, 0, 0)

static __device__ __forceinline__ float bf2f(unsigned short b) {
    return __uint_as_float(((unsigned)b) << 16);
}
static __device__ __forceinline__ unsigned short f2bf(float x) {  // RNE
    unsigned u = __float_as_uint(x);
    return (unsigned short)((u + 0x7FFF + ((u >> 16) & 1)) >> 16);
}
static __device__ __forceinline__ void gload16(const void* g, void* l) {
    __builtin_amdgcn_global_load_lds((const __attribute__((address_space(1))) void*)g,
                                     (__attribute__((address_space(3))) void*)l, 16, 0, 0);
}

// ---------------- K1: normalize + bf16 hi/lo split; zero S and done ----------------
__global__ __launch_bounds__(256) void normalize_k(const float* __restrict__ x1,
                                                   const float* __restrict__ x2,
                                                   unsigned short* __restrict__ Whi,
                                                   unsigned short* __restrict__ Wlo,
                                                   float* __restrict__ S,
                                                   unsigned* __restrict__ done) {
    if (blockIdx.x < 32) S[(blockIdx.x << 8) | threadIdx.x] = 0.f;   // 32*256 = 8192
    if (blockIdx.x == 32 && threadIdx.x < NTILE) done[threadIdx.x] = 0u;

    int row  = (int)((blockIdx.x * blockDim.x + threadIdx.x) >> 6);
    int lane = threadIdx.x & 63;
    const float* src = (row < N_ROWS) ? (x1 + (size_t)row * D)
                                      : (x2 + (size_t)(row - N_ROWS) * D);
    float4 v = ((const float4*)src)[lane];
    float ss = v.x * v.x + v.y * v.y + v.z * v.z + v.w * v.w;
    #pragma unroll
    for (int off = 32; off > 0; off >>= 1) ss += __shfl_xor(ss, off);
    float scale = 1.0f / fmaxf(sqrtf(ss), 1e-8f);
    float a[4] = {v.x * scale, v.y * scale, v.z * scale, v.w * scale};
    ushort4 h, l;
    unsigned short* hp = (unsigned short*)&h;
    unsigned short* lp = (unsigned short*)&l;
    #pragma unroll
    for (int i = 0; i < 4; ++i) {
        hp[i] = f2bf(a[i]);
        lp[i] = f2bf(a[i] - bf2f(hp[i]));
    }
    ((ushort4*)(Whi + (size_t)row * D))[lane] = h;
    ((ushort4*)(Wlo + (size_t)row * D))[lane] = l;
}

// Finalize 128 rows of a row-block: loss = log(S) + 10 - 10*pos_dot.
// S reads are cache-bypassing relaxed atomic loads (coherent-point values).
static __device__ __forceinline__ void finalize_rows(int b,
        const unsigned short* __restrict__ Whi, const unsigned short* __restrict__ Wlo,
        const float* __restrict__ S, float* __restrict__ out, int wv, int lane) {
    for (int r = wv; r < 128; r += 4) {                 // 4 waves x 32 rows
        int row = b * 128 + r;
        int partner = (row < N_ROWS) ? row + N_ROWS : row - N_ROWS;
        ushort4 ah = ((const ushort4*)(Whi + (size_t)row * D))[lane];
        ushort4 al = ((const ushort4*)(Wlo + (size_t)row * D))[lane];
        ushort4 bh = ((const ushort4*)(Whi + (size_t)partner * D))[lane];
        ushort4 bl = ((const ushort4*)(Wlo + (size_t)partner * D))[lane];
        const unsigned short* ahp = (const unsigned short*)&ah;
        const unsigned short* alp = (const unsigned short*)&al;
        const unsigned short* bhp = (const unsigned short*)&bh;
        const unsigned short* blp = (const unsigned short*)&bl;
        float d = 0.f;
        #pragma unroll
        for (int i = 0; i < 4; ++i) {
            float a = bf2f(ahp[i]) + bf2f(alp[i]);
            float bb = bf2f(bhp[i]) + bf2f(blp[i]);
            d = fmaf(a, bb, d);
        }
        #pragma unroll
        for (int off = 32; off > 0; off >>= 1) d += __shfl_xor(d, off);
        if (lane == 0) {
            float sval = __hip_atomic_load(&S[row], __ATOMIC_RELAXED,
                                           __HIP_MEMORY_SCOPE_AGENT);
            out[row] = logf(sval) + 10.0f - 10.0f * d;
        }
    }
}

// ---------------- K2: triangular Gram tiles + exp sums + last-block finalize ----
// Grid: 2080 blocks (XCD-swizzled), 4 waves (2x2). Tile body identical to R6
// (62.3 us verified): swizzled granules, global_load_lds w16, conflict-free.
__global__ __launch_bounds__(256, 3) void nce_partial_k(const unsigned short* __restrict__ Whi,
                                                        const unsigned short* __restrict__ Wlo,
                                                        float* __restrict__ S,
                                                        unsigned* __restrict__ done,
                                                        float* __restrict__ out) {
    __shared__ unsigned short tile[4][4096];   // Ahi, Alo, Bhi, Blo: 128x32 bf16, swizzled
    __shared__ float Srow[128];
    __shared__ float Scol[128];
    __shared__ int win_i, win_j;

    const int tid  = threadIdx.x;
    const int wid  = tid >> 6, lane = tid & 63;
    const int lr   = lane & 15, lg = lane >> 4;
    const int wr   = wid >> 1,  wc = wid & 1;

    // XCD-contiguous triangular tile id (2080 % 8 == 0 -> bijective)
    const int t = (blockIdx.x & 7) * (NTRI / 8) + (blockIdx.x >> 3);
    #define FPC(i) ((i) * NTILE - (i) * ((i) - 1) / 2)
    int bi = (int)((129.0f - sqrtf((float)(129 * 129 - 8 * t))) * 0.5f);
    while (FPC(bi + 1) <= t) ++bi;
    while (FPC(bi) > t) --bi;
    const int bj = bi + (t - FPC(bi));
    const int q0 = bi * 128, c0 = bj * 128;
    const bool offdiag = (bi != bj);

    if (tid < 128) { Srow[tid] = 0.f; Scol[tid] = 0.f; }

    f32x4 acc[4][4];
    #pragma unroll
    for (int i = 0; i < 4; ++i)
        #pragma unroll
        for (int j = 0; j < 4; ++j) acc[i][j] = (f32x4)0.f;

    // staging source offsets (pre-swizzled so LDS dest stays linear; rule #21)
    const int j0 = tid, j1 = tid + 256;
    const int r0 = j0 >> 2, g0 = (j0 & 3) ^ ((r0 >> 1) & 3);
    const int r1 = j1 >> 2, g1 = (j1 & 3) ^ ((r1 >> 1) & 3);
    const size_t soff0 = (size_t)r0 * D + g0 * 8;
    const size_t soff1 = (size_t)r1 * D + g1 * 8;
    const unsigned short* srcAh = Whi + (size_t)q0 * D;
    const unsigned short* srcAl = Wlo + (size_t)q0 * D;
    const unsigned short* srcBh = Whi + (size_t)c0 * D;
    const unsigned short* srcBl = Wlo + (size_t)c0 * D;
    const unsigned db0 = (unsigned)(tid & ~63) * 16u;          // wave-uniform LDS byte base
    const unsigned db1 = db0 + 256u * 16u;

    // fragment LDS byte offsets: slot(row,g) = row*4 + (g ^ ((row>>1)&3)) -> conflict-free
    int offA[4], offB[4];
    #pragma unroll
    for (int s = 0; s < 4; ++s) {
        int rowA = wr * 64 + s * 16 + lr;
        int rowB = wc * 64 + s * 16 + lr;
        int x = lg ^ ((lr >> 1) & 3);
        offA[s] = (rowA * 4 + x) * 16;
        offB[s] = (rowB * 4 + x) * 16;
    }

    for (int kc = 0; kc < D; kc += 32) {
        __syncthreads();   // previous chunk's reads done -> LDS reusable
        gload16(srcAh + soff0 + kc, (char*)&tile[0][0] + db0);
        gload16(srcAh + soff1 + kc, (char*)&tile[0][0] + db1);
        gload16(srcAl + soff0 + kc, (char*)&tile[1][0] + db0);
        gload16(srcAl + soff1 + kc, (char*)&tile[1][0] + db1);
        gload16(srcBh + soff0 + kc, (char*)&tile[2][0] + db0);
        gload16(srcBh + soff1 + kc, (char*)&tile[2][0] + db1);
        gload16(srcBl + soff0 + kc, (char*)&tile[3][0] + db0);
        gload16(srcBl + soff1 + kc, (char*)&tile[3][0] + db1);
        __syncthreads();   // compiler drains vmcnt before s_barrier

        bf16x8 bh[4], bl[4];
        #pragma unroll
        for (int sj = 0; sj < 4; ++sj) {
            bh[sj] = *(const bf16x8*)((const char*)&tile[2][0] + offB[sj]);
            bl[sj] = *(const bf16x8*)((const char*)&tile[3][0] + offB[sj]);
        }
        #pragma unroll
        for (int si = 0; si < 4; ++si) {
            bf16x8 ah = *(const bf16x8*)((const char*)&tile[0][0] + offA[si]);
            bf16x8 al = *(const bf16x8*)((const char*)&tile[1][0] + offA[si]);
            #pragma unroll
            for (int sj = 0; sj < 4; ++sj) {
                acc[si][sj] = MFMA16(ah, bh[sj], acc[si][sj]);
                acc[si][sj] = MFMA16(ah, bl[sj], acc[si][sj]);
                acc[si][sj] = MFMA16(al, bh[sj], acc[si][sj]);
            }
        }
    }

    // epilogue: exp + self-mask; row-sums always, col-sums for off-diag tiles.
    // C/D map: row = (lane>>4)*4 + reg, col = lane&15
    float rs[4][4];
    float cs[4] = {0.f, 0.f, 0.f, 0.f};
    #pragma unroll
    for (int si = 0; si < 4; ++si)
        #pragma unroll
        for (int r = 0; r < 4; ++r) rs[si][r] = 0.f;

    #pragma unroll
    for (int si = 0; si < 4; ++si) {
        int grb = q0 + wr * 64 + si * 16 + lg * 4;
        #pragma unroll
        for (int sj = 0; sj < 4; ++sj) {
            int gc = c0 + wc * 64 + sj * 16 + lr;
            #pragma unroll
            for (int r = 0; r < 4; ++r) {
                float e = __expf(fmaf(10.f, acc[si][sj][r], -10.f));
                e = (grb + r == gc) ? 0.f : e;
                rs[si][r] += e;
                cs[sj]    += e;
            }
        }
    }
    #pragma unroll
    for (int off = 1; off < 16; off <<= 1)
        #pragma unroll
        for (int si = 0; si < 4; ++si)
            #pragma unroll
            for (int r = 0; r < 4; ++r) rs[si][r] += __shfl_xor(rs[si][r], off);
    if (lr == 0) {
        #pragma unroll
        for (int si = 0; si < 4; ++si)
            #pragma unroll
            for (int r = 0; r < 4; ++r)
                atomicAdd(&Srow[wr * 64 + si * 16 + lg * 4 + r], rs[si][r]);
    }
    if (offdiag) {
        #pragma unroll
        for (int sj = 0; sj < 4; ++sj) {
            cs[sj] += __shfl_xor(cs[sj], 16);
            cs[sj] += __shfl_xor(cs[sj], 32);
        }
        if (lg == 0) {
            #pragma unroll
            for (int sj = 0; sj < 4; ++sj)
                atomicAdd(&Scol[wc * 64 + sj * 16 + lr], cs[sj]);
        }
    }
    __syncthreads();
    if (tid < 128) {
        atomicAdd(&S[q0 + tid], Srow[tid]);         // device-scope, cache-bypassing
        if (offdiag) atomicAdd(&S[c0 + tid], Scol[tid]);
    }
    __syncthreads();   // drains vmcnt for ALL waves -> block's S-adds complete
                       // at the coherent point before lane0's counter add below.

    // completion counters, ALL RELAXED (no fences -> no buffer_inv/wbl2).
    // Coherent-point serialization: winner seeing old==63 implies all 64
    // contributors' S-adds (drained pre-counter) are complete.
    if (tid == 0) {
        unsigned oi = __hip_atomic_fetch_add(&done[bi], 1u, __ATOMIC_RELAXED,
                                             __HIP_MEMORY_SCOPE_AGENT);
        win_i = (oi == 63u);
        win_j = 0;
        if (offdiag) {
            unsigned oj = __hip_atomic_fetch_add(&done[bj], 1u, __ATOMIC_RELAXED,
                                                 __HIP_MEMORY_SCOPE_AGENT);
            win_j = (oj == 63u);
        }
    }
    __syncthreads();
    if (win_i) finalize_rows(bi, Whi, Wlo, S, out, wid, lane);
    if (win_j) finalize_rows(bj, Whi, Wlo, S, out, wid, lane);
}

extern "C" void kernel_launch(void* const* d_in, const int* in_sizes, int n_in,
                              void* d_out, int out_size, void* d_ws, size_t ws_size,
                              hipStream_t stream) {
    const float* x1 = (const float*)d_in[0];
    const float* x2 = (const float*)d_in[1];
    float* out = (float*)d_out;

    unsigned short* Whi = (unsigned short*)d_ws;                    // 4 MB
    unsigned short* Wlo = Whi + (size_t)TWO_N * D;                  // 4 MB
    float* S = (float*)(Wlo + (size_t)TWO_N * D);                   // 32 KB
    unsigned* done = (unsigned*)(S + TWO_N);                        // 64 u32

    normalize_k<<<TWO_N / 4, 256, 0, stream>>>(x1, x2, Whi, Wlo, S, done);
    nce_partial_k<<<NTRI, 256, 0, stream>>>(Whi, Wlo, S, done, out);
}